// Round 7
// baseline (405.849 us; speedup 1.0000x reference)
//
#include <hip/hip_runtime.h>
#include <math.h>

#define SEQ   2048
#define DM    1024
#define NH    16
#define DH    64
#define DFF   4096
#define KVSPLIT 4

typedef __bf16 bf16;
using bf16x8 = __attribute__((ext_vector_type(8))) __bf16;
using f32x4  = __attribute__((ext_vector_type(4))) float;

__device__ __forceinline__ unsigned short f2bfu(float f) {
    unsigned int u = __float_as_uint(f);
    u += 0x7FFF + ((u >> 16) & 1);          // round-to-nearest-even
    return (unsigned short)(u >> 16);
}
__device__ __forceinline__ bf16 f2bf(float f) {
    unsigned short s = f2bfu(f);
    return __builtin_bit_cast(bf16, s);
}

// async global->LDS, 16B per lane. lds base must be wave-uniform; HW adds lane*16.
__device__ __forceinline__ void gll16(const bf16* g, bf16* lds_base) {
    __builtin_amdgcn_global_load_lds(
        (const __attribute__((address_space(1))) unsigned int*)g,
        (__attribute__((address_space(3))) unsigned int*)lds_base, 16, 0, 0);
}

// ---------------------------------------------------------------------------
// fp32 -> bf16 conversions
// ---------------------------------------------------------------------------
__global__ __launch_bounds__(256) void conv_k(const float* __restrict__ src,
                                              bf16* __restrict__ dst, int n) {
    int i = (blockIdx.x * 256 + threadIdx.x) * 4;
    if (i >= n) return;
    float4 v = *(const float4*)(src + i);
    ushort4 o;
    o.x = f2bfu(v.x); o.y = f2bfu(v.y); o.z = f2bfu(v.z); o.w = f2bfu(v.w);
    *(ushort4*)((unsigned short*)dst + i) = o;
}

struct ConvSeg  { const float* src; bf16* dst; int n; };
struct ConvSegs { ConvSeg s[6]; };

__global__ __launch_bounds__(256) void conv_multi_k(ConvSegs cs) {
    ConvSeg sg = cs.s[blockIdx.y];
    int i = (blockIdx.x * 256 + threadIdx.x) * 4;
    if (i >= sg.n) return;
    float4 v = *(const float4*)(sg.src + i);
    ushort4 o;
    o.x = f2bfu(v.x); o.y = f2bfu(v.y); o.z = f2bfu(v.z); o.w = f2bfu(v.w);
    *(ushort4*)((unsigned short*)sg.dst + i) = o;
}

// ---------------------------------------------------------------------------
// bf16 MFMA GEMM (full-K): C = A @ W^T + bias (+relu). z batches weight sets.
// ---------------------------------------------------------------------------
struct GemmPtrs {
    const bf16* W[3];
    const float* bias[3];
    float* out32[3];
    bf16*  out16[3];
};

template<int BM, int BN>
__global__ __launch_bounds__(256) void gemm_bf16_k(
    const bf16* __restrict__ A, GemmPtrs p, int N, int K, int relu)
{
    constexpr int TM = BM / 32;
    constexpr int TN = BN / 32;
    __shared__ bf16 As[BM][32];
    __shared__ bf16 Ws[BN][32];

    const int t    = threadIdx.x;
    const int lane = t & 63;
    const int wave = t >> 6;
    const int quad = lane >> 4;
    const int l15  = lane & 15;
    const int wm   = (wave >> 1) * (BM / 2);
    const int wn   = (wave & 1) * (BN / 2);
    const int m0   = blockIdx.y * BM;
    const int n0   = blockIdx.x * BN;
    const bf16* __restrict__ W = p.W[blockIdx.z];

    f32x4 acc[TM][TN];
    #pragma unroll
    for (int i = 0; i < TM; ++i)
        #pragma unroll
        for (int j = 0; j < TN; ++j)
            acc[i][j] = f32x4{0.f, 0.f, 0.f, 0.f};

    for (int k0 = 0; k0 < K; k0 += 32) {
        #pragma unroll
        for (int s = 0; s < BM / 64; ++s) {
            int base = s * 256 + wave * 64;
            int idx  = base + lane;
            gll16(A + (long)(m0 + (idx >> 2)) * K + k0 + (idx & 3) * 8,
                  &As[0][0] + (long)base * 8);
        }
        #pragma unroll
        for (int s = 0; s < BN / 64; ++s) {
            int base = s * 256 + wave * 64;
            int idx  = base + lane;
            gll16(W + (long)(n0 + (idx >> 2)) * K + k0 + (idx & 3) * 8,
                  &Ws[0][0] + (long)base * 8);
        }
        __syncthreads();

        bf16x8 a[TM], b[TN];
        #pragma unroll
        for (int i = 0; i < TM; ++i)
            a[i] = *(const bf16x8*)&As[wm + i * 16 + l15][quad * 8];
        #pragma unroll
        for (int j = 0; j < TN; ++j)
            b[j] = *(const bf16x8*)&Ws[wn + j * 16 + l15][quad * 8];
        #pragma unroll
        for (int i = 0; i < TM; ++i)
            #pragma unroll
            for (int j = 0; j < TN; ++j)
                acc[i][j] = __builtin_amdgcn_mfma_f32_16x16x32_bf16(
                    a[i], b[j], acc[i][j], 0, 0, 0);
        __syncthreads();
    }

    float* o32 = p.out32[blockIdx.z];
    bf16*  o16 = p.out16[blockIdx.z];
    const float* bias = p.bias[blockIdx.z];
    #pragma unroll
    for (int j = 0; j < TN; ++j) {
        int n = n0 + wn + j * 16 + l15;
        float bv = bias[n];
        #pragma unroll
        for (int i = 0; i < TM; ++i) {
            #pragma unroll
            for (int r = 0; r < 4; ++r) {
                int m = m0 + wm + i * 16 + quad * 4 + r;
                float v = acc[i][j][r] + bv;
                if (relu) v = fmaxf(v, 0.f);
                if (o32) o32[(long)m * N + n] = v;
                if (o16) o16[(long)m * N + n] = f2bf(v);
            }
        }
    }
}

// ---------------------------------------------------------------------------
// Split-K GEMM: blockIdx.z owns K-slice; writes fp32 partial to part + z*MN.
// ---------------------------------------------------------------------------
template<int BM, int BN, int KS>
__global__ __launch_bounds__(256) void gemm_splitk_k(
    const bf16* __restrict__ A, const bf16* __restrict__ W,
    float* __restrict__ part, int N, int K)
{
    constexpr int TM = BM / 32;
    constexpr int TN = BN / 32;
    __shared__ bf16 As[BM][32];
    __shared__ bf16 Ws[BN][32];

    const int t    = threadIdx.x;
    const int lane = t & 63;
    const int wave = t >> 6;
    const int quad = lane >> 4;
    const int l15  = lane & 15;
    const int wm   = (wave >> 1) * (BM / 2);
    const int wn   = (wave & 1) * (BN / 2);
    const int m0   = blockIdx.y * BM;
    const int n0   = blockIdx.x * BN;
    const int Kp   = K / KS;
    const int klo  = blockIdx.z * Kp;
    const long MN  = (long)gridDim.y * BM * N;

    f32x4 acc[TM][TN];
    #pragma unroll
    for (int i = 0; i < TM; ++i)
        #pragma unroll
        for (int j = 0; j < TN; ++j)
            acc[i][j] = f32x4{0.f, 0.f, 0.f, 0.f};

    for (int k0 = klo; k0 < klo + Kp; k0 += 32) {
        #pragma unroll
        for (int s = 0; s < BM / 64; ++s) {
            int base = s * 256 + wave * 64;
            int idx  = base + lane;
            gll16(A + (long)(m0 + (idx >> 2)) * K + k0 + (idx & 3) * 8,
                  &As[0][0] + (long)base * 8);
        }
        #pragma unroll
        for (int s = 0; s < BN / 64; ++s) {
            int base = s * 256 + wave * 64;
            int idx  = base + lane;
            gll16(W + (long)(n0 + (idx >> 2)) * K + k0 + (idx & 3) * 8,
                  &Ws[0][0] + (long)base * 8);
        }
        __syncthreads();

        bf16x8 a[TM], b[TN];
        #pragma unroll
        for (int i = 0; i < TM; ++i)
            a[i] = *(const bf16x8*)&As[wm + i * 16 + l15][quad * 8];
        #pragma unroll
        for (int j = 0; j < TN; ++j)
            b[j] = *(const bf16x8*)&Ws[wn + j * 16 + l15][quad * 8];
        #pragma unroll
        for (int i = 0; i < TM; ++i)
            #pragma unroll
            for (int j = 0; j < TN; ++j)
                acc[i][j] = __builtin_amdgcn_mfma_f32_16x16x32_bf16(
                    a[i], b[j], acc[i][j], 0, 0, 0);
        __syncthreads();
    }

    float* o = part + (long)blockIdx.z * MN;
    #pragma unroll
    for (int j = 0; j < TN; ++j) {
        int n = n0 + wn + j * 16 + l15;
        #pragma unroll
        for (int i = 0; i < TM; ++i)
            #pragma unroll
            for (int r = 0; r < 4; ++r) {
                int m = m0 + wm + i * 16 + quad * 4 + r;
                o[(long)m * N + n] = acc[i][j][r];
            }
    }
}

// ---------------------------------------------------------------------------
// Flash attention, S^T formulation. K fragments load DIRECT from global
// (A-operand, rows contiguous in d); only V (transposed, paired b32) and the
// per-wave P tile (packed b64) go through LDS. Fixed-max softmax, kv-split.
// LDS ~19 KB -> 8 blocks/CU.
// ---------------------------------------------------------------------------
__global__ __launch_bounds__(256) void attn_mfma_k(
    const bf16* __restrict__ Q, const bf16* __restrict__ Kg,
    const bf16* __restrict__ Vg, bf16* __restrict__ Opart,
    float* __restrict__ lpart)
{
    __shared__ bf16 Vt[64][72];      // [d][key-swizzled], stride 144 B
    __shared__ bf16 Ps[4][16][76];   // per-wave P[q][key], stride 152 B

    const int t    = threadIdx.x;
    const int lane = t & 63;
    const int wave = t >> 6;
    const int quad = lane >> 4;
    const int l15  = lane & 15;
    const int h    = blockIdx.y;
    const int q0   = blockIdx.x * 64;
    const int spl  = blockIdx.z;
    const int cb   = h * DH;
    const long SD  = (long)SEQ * DM;

    // Q as B-operand: lane n=l15 -> q-row, quad -> d-octet
    const int qrow = q0 + wave * 16 + l15;
    bf16x8 bQ[2];
    #pragma unroll
    for (int kh = 0; kh < 2; ++kh)
        bQ[kh] = *(const bf16x8*)(Q + (long)qrow * DM + cb + kh * 32 + quad * 8);

    // ones column (n=0) for row sums
    bf16 oneb = f2bf(l15 == 0 ? 1.0f : 0.0f);
    bf16x8 bOnes;
    #pragma unroll
    for (int j = 0; j < 8; ++j) bOnes[j] = oneb;

    f32x4 o_acc[4], l_acc;
    #pragma unroll
    for (int dt = 0; dt < 4; ++dt) o_acc[dt] = f32x4{0.f, 0.f, 0.f, 0.f};
    l_acc = f32x4{0.f, 0.f, 0.f, 0.f};

    const float SCL = 0.18033688f;   // 0.125 * log2(e)
    // V staging mapping: pp = key-pair 0..31, dgv = d-octet 0..7
    const int pp  = t & 31;
    const int dgv = t >> 5;
    const int kv_lo = spl * (SEQ / KVSPLIT);
    const int kv_hi = kv_lo + SEQ / KVSPLIT;

    for (int kv0 = kv_lo; kv0 < kv_hi; kv0 += 64) {
        __syncthreads();   // prior tile's Vt reads complete

        // ---- stage V: two adjacent keys, packed pair stores ----
        const bf16* vp = Vg + (long)(kv0 + 2 * pp) * DM + cb + dgv * 8;
        bf16x8 v0 = *(const bf16x8*)(vp);
        bf16x8 v1 = *(const bf16x8*)(vp + DM);
        // column octet XOR-swizzle: key-octet ^ d-octet
        int col0 = ((((pp >> 2) ^ dgv) << 3) | ((pp & 3) << 1));
        #pragma unroll
        for (int j = 0; j < 8; ++j) {
            unsigned pk = (unsigned)__builtin_bit_cast(unsigned short, v0[j]) |
                          ((unsigned)__builtin_bit_cast(unsigned short, v1[j]) << 16);
            *(unsigned*)&Vt[dgv * 8 + j][col0] = pk;
        }

        // ---- S^T = K @ Q^T: A = K rows direct from global ----
        f32x4 s4[4];
        #pragma unroll
        for (int kt = 0; kt < 4; ++kt) {
            const bf16* kp = Kg + (long)(kv0 + kt * 16 + l15) * DM + cb + quad * 8;
            bf16x8 aK0 = *(const bf16x8*)(kp);
            bf16x8 aK1 = *(const bf16x8*)(kp + 32);
            f32x4 s = f32x4{0.f, 0.f, 0.f, 0.f};
            s = __builtin_amdgcn_mfma_f32_16x16x32_bf16(aK0, bQ[0], s, 0, 0, 0);
            s = __builtin_amdgcn_mfma_f32_16x16x32_bf16(aK1, bQ[1], s, 0, 0, 0);
            s4[kt] = s;   // S^T[key=kt*16+quad*4+r][q=l15]
        }

        // ---- P = exp(S/8), pack 4 keys -> one b64 store per kt ----
        #pragma unroll
        for (int kt = 0; kt < 4; ++kt) {
            unsigned long long pk = 0;
            #pragma unroll
            for (int r = 0; r < 4; ++r) {
                float pv = exp2f(s4[kt][r] * SCL);
                pk |= (unsigned long long)f2bfu(pv) << (r * 16);
            }
            *(unsigned long long*)&Ps[wave][l15][kt * 16 + quad * 4] = pk;
        }
        // per-wave read-back as A-operand (lane m=l15 -> q, k=key)
        bf16x8 aP[2];
        aP[0] = *(const bf16x8*)&Ps[wave][l15][quad * 8];
        aP[1] = *(const bf16x8*)&Ps[wave][l15][32 + quad * 8];

        // ---- row sums l += P . 1 ----
        l_acc = __builtin_amdgcn_mfma_f32_16x16x32_bf16(aP[0], bOnes, l_acc, 0, 0, 0);
        l_acc = __builtin_amdgcn_mfma_f32_16x16x32_bf16(aP[1], bOnes, l_acc, 0, 0, 0);

        __syncthreads();   // Vt stores visible to all waves

        // ---- O += P @ V ----
        #pragma unroll
        for (int dt = 0; dt < 4; ++dt) {
            int d   = dt * 16 + l15;
            int dgr = d >> 3;
            bf16x8 vf0 = *(const bf16x8*)&Vt[d][((quad) ^ dgr) * 8];
            bf16x8 vf1 = *(const bf16x8*)&Vt[d][((4 + quad) ^ dgr) * 8];
            o_acc[dt] = __builtin_amdgcn_mfma_f32_16x16x32_bf16(aP[0], vf0, o_acc[dt], 0, 0, 0);
            o_acc[dt] = __builtin_amdgcn_mfma_f32_16x16x32_bf16(aP[1], vf1, o_acc[dt], 0, 0, 0);
        }
    }

    // store unnormalized partials; l for row quad*4+r lives in lane quad*16
    #pragma unroll
    for (int r = 0; r < 4; ++r) {
        int row = q0 + wave * 16 + quad * 4 + r;
        #pragma unroll
        for (int dt = 0; dt < 4; ++dt)
            Opart[(long)spl * SD + (long)row * DM + cb + dt * 16 + l15] =
                f2bf(o_acc[dt][r]);
        if (l15 == 0)
            lpart[((long)spl * NH + h) * SEQ + row] = l_acc[r];
    }
}

__global__ __launch_bounds__(256) void attn_reduce_k(
    const bf16* __restrict__ Opart, const float* __restrict__ lpart,
    bf16* __restrict__ O)
{
    const long SD = (long)SEQ * DM;
    long i = ((long)blockIdx.x * 256 + threadIdx.x) * 8;
    int row = (int)(i / DM);
    int h   = (int)((i % DM) / DH);

    float l = 0.f;
    #pragma unroll
    for (int k = 0; k < KVSPLIT; ++k)
        l += lpart[((long)k * NH + h) * SEQ + row];
    float inv = 1.f / l;

    float acc[8] = {};
    #pragma unroll
    for (int k = 0; k < KVSPLIT; ++k) {
        bf16x8 v = *(const bf16x8*)(Opart + (long)k * SD + i);
        #pragma unroll
        for (int j = 0; j < 8; ++j) acc[j] += (float)v[j];
    }
    bf16x8 o;
    #pragma unroll
    for (int j = 0; j < 8; ++j) o[j] = f2bf(acc[j] * inv);
    *(bf16x8*)(O + i) = o;
}

// ---------------------------------------------------------------------------
// Fused split-K reduce + bias + residual + LayerNorm. One block per row.
// ---------------------------------------------------------------------------
template<int NS>
__global__ __launch_bounds__(256) void ln_red_k(
    const float* __restrict__ part, const float* __restrict__ bias,
    const float* __restrict__ res, const float* __restrict__ g,
    const float* __restrict__ b, float* __restrict__ out32,
    bf16* __restrict__ out16)
{
    const long SD = (long)SEQ * DM;
    const int row = blockIdx.x;
    const int t   = threadIdx.x;
    const long off = (long)row * DM + (t << 2);

    float4 v = *(const float4*)(res + off);
    float4 bv0 = *(const float4*)(bias + (t << 2));
    v.x += bv0.x; v.y += bv0.y; v.z += bv0.z; v.w += bv0.w;
    #pragma unroll
    for (int z = 0; z < NS; ++z) {
        float4 pz = *(const float4*)(part + z * SD + off);
        v.x += pz.x; v.y += pz.y; v.z += pz.z; v.w += pz.w;
    }

    float s1 = v.x + v.y + v.z + v.w;
    float s2 = v.x * v.x + v.y * v.y + v.z * v.z + v.w * v.w;
    #pragma unroll
    for (int off2 = 32; off2 > 0; off2 >>= 1) {
        s1 += __shfl_xor(s1, off2);
        s2 += __shfl_xor(s2, off2);
    }
    __shared__ float red[8];
    int wid = t >> 6, lid = t & 63;
    if (lid == 0) { red[wid] = s1; red[4 + wid] = s2; }
    __syncthreads();
    s1 = red[0] + red[1] + red[2] + red[3];
    s2 = red[4] + red[5] + red[6] + red[7];

    float mu   = s1 * (1.f / DM);
    float var  = s2 * (1.f / DM) - mu * mu;
    float rstd = rsqrtf(var + 1e-5f);

    float4 gv = *(const float4*)(g + (t << 2));
    float4 bv = *(const float4*)(b + (t << 2));
    float4 ov;
    ov.x = (v.x - mu) * rstd * gv.x + bv.x;
    ov.y = (v.y - mu) * rstd * gv.y + bv.y;
    ov.z = (v.z - mu) * rstd * gv.z + bv.z;
    ov.w = (v.w - mu) * rstd * gv.w + bv.w;
    if (out32) *(float4*)(out32 + off) = ov;
    if (out16) {
        ushort4 o;
        o.x = f2bfu(ov.x); o.y = f2bfu(ov.y); o.z = f2bfu(ov.z); o.w = f2bfu(ov.w);
        *(ushort4*)((unsigned short*)out16 + off) = o;
    }
}

// ---------------------------------------------------------------------------
extern "C" void kernel_launch(void* const* d_in, const int* in_sizes, int n_in,
                              void* d_out, int out_size, void* d_ws, size_t ws_size,
                              hipStream_t stream)
{
    const float* x       = (const float*)d_in[0];
    const float* q_in_w  = (const float*)d_in[1];
    const float* q_in_b  = (const float*)d_in[2];
    const float* k_in_w  = (const float*)d_in[3];
    const float* k_in_b  = (const float*)d_in[4];
    const float* v_in_w  = (const float*)d_in[5];
    const float* v_in_b  = (const float*)d_in[6];
    const float* out_w   = (const float*)d_in[7];
    const float* out_b   = (const float*)d_in[8];
    const float* ffn1_w  = (const float*)d_in[9];
    const float* ffn1_b  = (const float*)d_in[10];
    const float* ffn2_w  = (const float*)d_in[11];
    const float* ffn2_b  = (const float*)d_in[12];
    const float* n1_g    = (const float*)d_in[13];
    const float* n1_b    = (const float*)d_in[14];
    const float* n2_g    = (const float*)d_in[15];
    const float* n2_b    = (const float*)d_in[16];
    const float* q_out_w = (const float*)d_in[17];
    const float* q_out_b = (const float*)d_in[18];
    const float* k_out_w = (const float*)d_in[19];
    const float* k_out_b = (const float*)d_in[20];
    const float* v_out_w = (const float*)d_in[21];
    const float* v_out_b = (const float*)d_in[22];

    float* out = (float*)d_out;
    const long SD = (long)SEQ * DM;
    const long MB = 1024 * 1024;

    // --- workspace layout, 48 MiB (identical lifetimes to round 6) ---
    char* w = (char*)d_ws;
    bf16*  xbf   = (bf16*)(w);
    float* lpart = (float*)(w);
    bf16*  qb    = (bf16*)(w + 4  * MB);
    bf16*  kb    = (bf16*)(w + 8  * MB);
    bf16*  vb    = (bf16*)(w + 12 * MB);
    bf16*  atnb  = (bf16*)(w + 16 * MB);
    float* h32   = (float*)(w);
    bf16*  h16   = (bf16*)(w + 8  * MB);
    float* P2    = (float*)(w + 8  * MB);
    bf16*  Opart = (bf16*)(w + 20 * MB);
    float* P1    = (float*)(w + 20 * MB);
    bf16*  f1    = (bf16*)(w + 24 * MB);
    bf16*  wqi   = (bf16*)(w + 32 * MB);
    bf16*  wki   = (bf16*)(w + 34 * MB);
    bf16*  wvi   = (bf16*)(w + 36 * MB);
    bf16*  wo    = (bf16*)(w + 38 * MB);
    bf16*  wf1   = (bf16*)(w + 40 * MB);
    bf16*  wf2   = (bf16*)(w + 40 * MB);
    bf16*  wqo   = (bf16*)(w + 24 * MB);
    bf16*  wko   = (bf16*)(w + 26 * MB);
    bf16*  wvo   = (bf16*)(w + 28 * MB);
    bf16*  ybf   = (bf16*)(w + 30 * MB);
    float* y32   = out + 3 * SD;

    dim3 blk(256);
    const int DD = DM * DM;

    // --- conv group 1 ---
    {
        ConvSegs cs;
        cs.s[0] = {x,      xbf, (int)SD};
        cs.s[1] = {q_in_w, wqi, DD};
        cs.s[2] = {k_in_w, wki, DD};
        cs.s[3] = {v_in_w, wvi, DD};
        cs.s[4] = {out_w,  wo,  DD};
        cs.s[5] = {ffn1_w, wf1, DM * DFF};
        conv_multi_k<<<dim3(DM * DFF / 1024, 6), blk, 0, stream>>>(cs);
    }

    // --- q/k/v in-projections (128x128, 384 blocks) ---
    {
        GemmPtrs p{};
        p.W[0] = wqi; p.W[1] = wki; p.W[2] = wvi;
        p.bias[0] = q_in_b; p.bias[1] = k_in_b; p.bias[2] = v_in_b;
        p.out16[0] = qb; p.out16[1] = kb; p.out16[2] = vb;
        gemm_bf16_k<128, 128><<<dim3(DM / 128, SEQ / 128, 3), blk, 0, stream>>>(
            xbf, p, DM, DM, 0);
    }

    // --- attention: kv-split x4 (2048 blocks) + reduce ---
    attn_mfma_k<<<dim3(SEQ / 64, NH, KVSPLIT), blk, 0, stream>>>(
        qb, kb, vb, Opart, lpart);
    attn_reduce_k<<<dim3((int)(SD / 2048)), blk, 0, stream>>>(Opart, lpart, atnb);

    // --- out-projection, split-K=2 (64x128, 512 blocks) -> P1 ---
    gemm_splitk_k<64, 128, 2><<<dim3(DM / 128, SEQ / 64, 2), blk, 0, stream>>>(
        atnb, wo, P1, DM, DM);

    // --- LN1 fused reduce ---
    ln_red_k<2><<<SEQ, blk, 0, stream>>>(P1, out_b, x, n1_g, n1_b, h32, h16);

    // --- FFN1 (128x128, 512 blocks, relu) ---
    {
        GemmPtrs p{};
        p.W[0] = wf1; p.bias[0] = ffn1_b; p.out16[0] = f1;
        gemm_bf16_k<128, 128><<<dim3(DFF / 128, SEQ / 128, 1), blk, 0, stream>>>(
            h16, p, DFF, DM, 1);
    }

    // --- conv wf2 ---
    conv_k<<<dim3(DM * DFF / 1024), blk, 0, stream>>>(ffn2_w, wf2, DM * DFF);

    // --- FFN2, split-K=2 (64x128, 512 blocks) -> P2 ---
    gemm_splitk_k<64, 128, 2><<<dim3(DM / 128, SEQ / 64, 2), blk, 0, stream>>>(
        f1, wf2, P2, DM, DFF);

    // --- conv group 3 ---
    {
        ConvSegs cs;
        cs.s[0] = {q_out_w, wqo, DD};
        cs.s[1] = {k_out_w, wko, DD};
        cs.s[2] = {v_out_w, wvo, DD};
        cs.s[3] = cs.s[0]; cs.s[4] = cs.s[0]; cs.s[5] = cs.s[0];
        conv_multi_k<<<dim3(DD / 1024, 3), blk, 0, stream>>>(cs);
    }

    // --- LN2 fused reduce ---
    ln_red_k<2><<<SEQ, blk, 0, stream>>>(P2, ffn2_b, h32, n2_g, n2_b, y32, ybf);

    // --- next-layer projections (128x128, 384 blocks) ---
    {
        GemmPtrs p{};
        p.W[0] = wqo; p.W[1] = wko; p.W[2] = wvo;
        p.bias[0] = q_out_b; p.bias[1] = k_out_b; p.bias[2] = v_out_b;
        p.out32[0] = out; p.out32[1] = out + SD; p.out32[2] = out + 2 * SD;
        gemm_bf16_k<128, 128><<<dim3(DM / 128, SEQ / 128, 3), blk, 0, stream>>>(
            ybf, p, DM, DM, 0);
    }
}